// Round 8
// baseline (637.584 us; speedup 1.0000x reference)
//
#include <hip/hip_runtime.h>

#define KDIM 1024
#define NDIM 4096

typedef __attribute__((ext_vector_type(4))) float f32x4;
typedef __attribute__((ext_vector_type(16))) float f32x16;
typedef __attribute__((ext_vector_type(8))) short s16x8;
typedef __attribute__((ext_vector_type(8))) unsigned short u16x8;

__device__ __forceinline__ unsigned short f2bf(float f) {
    union { float f; unsigned u; } v; v.f = f;
    unsigned r = v.u + 0x7FFFu + ((v.u >> 16) & 1u);
    return (unsigned short)(r >> 16);
}

#define GLDS(gsrc, ldst)                                                        \
    __builtin_amdgcn_global_load_lds(                                           \
        (const __attribute__((address_space(1))) unsigned int*)(gsrc),          \
        (__attribute__((address_space(3))) unsigned int*)(ldst), 16, 0, 0)

#define SBAR() __builtin_amdgcn_s_barrier()
#define VMW(n) asm volatile("s_waitcnt vmcnt(" #n ")" ::: "memory")

__device__ __forceinline__ void row_coeffs(int o, const float* w,
                                           float& rp0, float& rp1, float& rp2) {
    rp2 = (o < 2048 ? w[6] : 0.f) + (o < 3072 ? w[7] : 0.f) + w[8];
    rp1 = rp2 + (o < 1536 ? w[3] : 0.f) + (o < 2304 ? w[4] : 0.f) + (o < 3072 ? w[5] : 0.f);
    rp0 = rp1 + (o < 1024 ? w[0] : 0.f) + (o < 1536 ? w[1] : 0.f) + (o < 2048 ? w[2] : 0.f);
}

__device__ __forceinline__ float row_bias_coef(int n, const float* w) {
    return (n < 1024 ? w[0] : 0.f) + (n < 1536 ? w[1] : 0.f)
         + (n < 2048 ? w[2] : 0.f) + (n < 1536 ? w[3] : 0.f)
         + (n < 2304 ? w[4] : 0.f) + (n < 3072 ? w[5] : 0.f)
         + (n < 2048 ? w[6] : 0.f) + (n < 3072 ? w[7] : 0.f) + w[8];
}

// ---------------- pre-pass: X f32 -> bf16 ----------------
__global__ __launch_bounds__(256) void prep_x(const float* __restrict__ X,
                                              unsigned short* __restrict__ XB, int n8) {
    int i = blockIdx.x * blockDim.x + threadIdx.x;
    const int stride = gridDim.x * blockDim.x;
    for (; i < n8; i += stride) {
        const f32x4* p = (const f32x4*)(X + (size_t)i * 8);
        f32x4 a = p[0], b = p[1];
        u16x8 o;
        o[0] = f2bf(a[0]); o[1] = f2bf(a[1]); o[2] = f2bf(a[2]); o[3] = f2bf(a[3]);
        o[4] = f2bf(b[0]); o[5] = f2bf(b[1]); o[6] = f2bf(b[2]); o[7] = f2bf(b[3]);
        *(u16x8*)(XB + (size_t)i * 8) = o;
    }
}

// ---------------- pre-pass: W_mix = W * coeff -> bf16 ----------------
__global__ __launch_bounds__(256) void prep_w(const float* __restrict__ W,
                                              const float* __restrict__ wts,
                                              unsigned short* __restrict__ WB) {
    const int g = blockIdx.x * blockDim.x + threadIdx.x;
    if (g >= NDIM * (KDIM / 8)) return;
    const int o = g >> 7, ig = g & 127;
    float w[9];
#pragma unroll
    for (int k = 0; k < 9; ++k) w[k] = wts[k];
    float rp0, rp1, rp2;
    row_coeffs(o, w, rp0, rp1, rp2);
    const float cf = ig < 64 ? rp0 : (ig < 96 ? rp1 : rp2);
    const f32x4* p = (const f32x4*)(W + (size_t)g * 8);
    f32x4 a = p[0], b = p[1];
    u16x8 ov;
    ov[0] = f2bf(a[0] * cf); ov[1] = f2bf(a[1] * cf); ov[2] = f2bf(a[2] * cf); ov[3] = f2bf(a[3] * cf);
    ov[4] = f2bf(b[0] * cf); ov[5] = f2bf(b[1] * cf); ov[6] = f2bf(b[2] * cf); ov[7] = f2bf(b[3] * cf);
    *(u16x8*)(WB + (size_t)g * 8) = ov;
}

// ---------------- main GEMM v8: 256x256 block, 4 waves, 128x128/wave, 32x32x16 MFMA ----------------
// Rationale (rounds 3-7 all ~30-35% MfmaUtil): at 128x64/wave, CU LDS traffic
// (96KB rd + 32KB wr per K-tile) equals the MFMA pipe (1240cy) -> hard ~50% cap.
// 128x128/wave halves A/B re-reads (64KB rd) and 32x32x16 MFMA cuts pipe to
// 1082cy -> MFMA-bound with margin. 1 wave/SIMD; latency hidden by frag-set
// ping-pong (read kt+1's 16 frags during kt's 32-MFMA cluster) + ring-4 LDS
// with counted VMW(8) (waits on loads issued a full K-tile earlier).
// LDS layout per buf (32KB): [A|B][kc 0..3][256 rows][8 bf16] -> GLDS dests
// linear; frag reads 512B-contiguous (2 lanes/bank = free). No swizzle needed.
// __launch_bounds__(256,1): 512-reg budget (acc 256 + 2 frag sets 128 + addr).
__global__ __launch_bounds__(256, 1) void mlv2_gemm_v8(
    const unsigned short* __restrict__ XB,
    const unsigned short* __restrict__ WB,
    const float* __restrict__ wts,
    const float* __restrict__ bias,
    float* __restrict__ Y)
{
    __shared__ unsigned short LDS[4 * 16384];   // 128 KiB: 4 bufs x (A 16KB + B 16KB)

    const int tid = (int)threadIdx.x;
    const int l   = tid & 63;
    const int w   = tid >> 6;      // wave 0..3
    const int wm  = w >> 1;        // 0..1
    const int wn  = w & 1;         // 0..1

    const int bid = (int)blockIdx.x;
    const int xcd = bid & 7;
    const int i   = bid >> 3;                // 0..255
    const int n_tile = xcd * 2 + (i & 1);    // XCD pinned to 2 n-tiles
    const int m_tile = i >> 1;               // pair shares m_tile
    const int m0 = m_tile * 256;
    const int n0 = n_tile * 256;

    // ---- frag-read offsets (ushort units). Lane l of frag (mt,ks):
    // A[row = wm*128+mt*32+(l&31)][kg = ks*2+(l>>5)] -> [kc][256][8] layout.
    unsigned offA[4][2], offB[4][2];
#pragma unroll
    for (int mt = 0; mt < 4; ++mt)
#pragma unroll
        for (int ks = 0; ks < 2; ++ks) {
            const unsigned kg = (unsigned)(ks * 2 + (l >> 5));
            offA[mt][ks] = (kg * 256 + (unsigned)(wm * 128 + mt * 32 + (l & 31))) * 8u;
            offB[mt][ks] = 8192u + (kg * 256 + (unsigned)(wn * 128 + mt * 32 + (l & 31))) * 8u;
        }

    // ---- staging: wave w stages A/B rows [64w, 64w+64), GLDS q covers kc=q.
    // dest chunk = q*256 + w*64 + lane (linear); src = row (m0+64w+l), cols q*8.
    const unsigned short* sA[4];
    const unsigned short* sB[4];
    unsigned dstA[4], dstB[4];
#pragma unroll
    for (int q = 0; q < 4; ++q) {
        sA[q] = XB + (size_t)(m0 + w * 64 + l) * KDIM + q * 8;
        sB[q] = WB + (size_t)(n0 + w * 64 + l) * KDIM + q * 8;
        dstA[q] = (unsigned)((q * 256 + w * 64) * 8);
        dstB[q] = 8192u + dstA[q];
    }

    auto stage = [&](int kt) {
        const unsigned bb = (unsigned)(kt & 3) * 16384u;
        const int ko = kt * 32;
#pragma unroll
        for (int q = 0; q < 4; ++q) {
            GLDS(sA[q] + ko, &LDS[bb + dstA[q]]);
            GLDS(sB[q] + ko, &LDS[bb + dstB[q]]);
        }
    };

    f32x16 acc[4][4];
#pragma unroll
    for (int mt = 0; mt < 4; ++mt)
#pragma unroll
        for (int nt = 0; nt < 4; ++nt)
#pragma unroll
            for (int r = 0; r < 16; ++r) acc[mt][nt][r] = 0.f;

    s16x8 aX[4][2], bX[4][2], aY[4][2], bY[4][2];   // two named frag sets

    auto rd = [&](s16x8 (&a)[4][2], s16x8 (&b)[4][2], int kt) {
        const unsigned bb = (unsigned)(kt & 3) * 16384u;
#pragma unroll
        for (int mt = 0; mt < 4; ++mt)
#pragma unroll
            for (int ks = 0; ks < 2; ++ks) {
                a[mt][ks] = *(const s16x8*)&LDS[bb + offA[mt][ks]];
                b[mt][ks] = *(const s16x8*)&LDS[bb + offB[mt][ks]];
            }
    };
    auto mm = [&](const s16x8 (&a)[4][2], const s16x8 (&b)[4][2]) {
        __builtin_amdgcn_s_setprio(1);
#pragma unroll
        for (int ks = 0; ks < 2; ++ks)
#pragma unroll
            for (int mt = 0; mt < 4; ++mt)
#pragma unroll
                for (int nt = 0; nt < 4; ++nt)
                    acc[mt][nt] = __builtin_amdgcn_mfma_f32_32x32x16_bf16(
                        a[mt][ks], b[nt][ks], acc[mt][nt], 0, 0, 0);
        __builtin_amdgcn_s_setprio(0);
    };

    // prologue: stage tiles 0,1,2 (24 loads); VMW(8) -> t0,t1 landed (t2 in flight)
    stage(0); stage(1); stage(2);
    VMW(8);
    SBAR();
    rd(aX, bX, 0);

    // steady (2x unroll = frag-set ping-pong). Per tile-iter kt:
    //   rd(kt+1) | stage(kt+3) | 32 MFMA(kt) | VMW(8) [tile kt+2 landed] | SBAR
    // Invariant after iter-kt barrier: tiles <= kt+2 globally visible; kt+3 in
    // flight (8 loads). Buffer overwritten at iter kt is buf[(kt-1)&3], whose
    // reads retired during iter kt-1's MFMA (lgkm FIFO) -- no race.
    for (int kt = 0; kt < 28; kt += 2) {
        rd(aY, bY, kt + 1);
        stage(kt + 3);
        mm(aX, bX);
        VMW(8); SBAR();

        rd(aX, bX, kt + 2);
        stage(kt + 4);
        mm(aY, bY);
        VMW(8); SBAR();
    }
    // kt=28: last stage (t31)
    rd(aY, bY, 29);
    stage(31);
    mm(aX, bX);
    VMW(8); SBAR();
    // kt=29: drain t31
    rd(aX, bX, 30);
    mm(aY, bY);
    VMW(0); SBAR();
    // kt=30
    rd(aY, bY, 31);
    mm(aX, bX);
    // kt=31
    mm(aY, bY);

    // ---- epilogue: Y = acc + bias[n]*rowcoef(n)
    // C/D layout (32x32): col = lane&31, row = (r&3) + 8*(r>>2) + 4*(lane>>5)
    float w9[9];
#pragma unroll
    for (int k = 0; k < 9; ++k) w9[k] = wts[k];
    const int colb = l & 31;
    const int rhi  = (l >> 5) * 4;
#pragma unroll
    for (int nt = 0; nt < 4; ++nt) {
        const int gn = n0 + wn * 128 + nt * 32 + colb;
        const float bc = bias[gn] * row_bias_coef(gn, w9);
#pragma unroll
        for (int mt = 0; mt < 4; ++mt) {
            const int rb = m0 + wm * 128 + mt * 32 + rhi;
#pragma unroll
            for (int r = 0; r < 16; ++r) {
                const int row = rb + (r & 3) + 8 * (r >> 2);
                Y[(size_t)row * NDIM + gn] = acc[mt][nt][r] + bc;
            }
        }
    }
}

// ---------------- fallback (round-1 fused kernel, validated) ----------------
__global__ __launch_bounds__(256, 2) void mlv2_gemm_v1(
    const float* __restrict__ X, const float* __restrict__ wts,
    const float* __restrict__ W, const float* __restrict__ bias,
    float* __restrict__ Y)
{
    __shared__ unsigned short Alds[2][4][128][8];
    __shared__ unsigned short Blds[2][4][128][8];
    const int tid = (int)threadIdx.x;
    const int bid = (int)blockIdx.x;
    const int wg  = (bid & 7) * 1024 + (bid >> 3);
    const int n_tile = wg & 31;
    const int m_tile = wg >> 5;
    float w[9];
#pragma unroll
    for (int k = 0; k < 9; ++k) w[k] = wts[k];
    const int srow = tid >> 1;
    const int scol = (tid & 1) << 4;
    const int kc0  = (tid & 1) << 1;
    const float* xp = X + (size_t)(m_tile * 128 + srow) * KDIM + scol;
    const float* wp = W + (size_t)(n_tile * 128 + srow) * KDIM + scol;
    const int orow = n_tile * 128 + srow;
    float rp0, rp1, rp2;
    row_coeffs(orow, w, rp0, rp1, rp2);
    const int lane = tid & 63, wv = tid >> 6;
    const int frow = lane & 15, kcl = lane >> 4;
    const int arow0 = (wv >> 1) * 64 + frow;
    const int brow0 = (wv & 1) * 64 + frow;
    auto coef = [&](int t) -> float { return t < 16 ? rp0 : (t < 24 ? rp1 : rp2); };
    auto stage_load = [&](int t, f32x4 a[4], f32x4 b[4]) {
        const f32x4* xq = (const f32x4*)(xp + t * 32);
        const f32x4* wq = (const f32x4*)(wp + t * 32);
#pragma unroll
        for (int j = 0; j < 4; ++j) { a[j] = xq[j]; b[j] = wq[j]; }
    };
    auto stage_write = [&](int buf, const f32x4 a[4], const f32x4 b[4], float cf) {
        u16x8 va[2], vb[2];
#pragma unroll
        for (int j = 0; j < 4; ++j)
#pragma unroll
            for (int e = 0; e < 4; ++e) {
                const int idx = j * 4 + e;
                va[idx >> 3][idx & 7] = f2bf(a[j][e]);
                vb[idx >> 3][idx & 7] = f2bf(b[j][e] * cf);
            }
        *(u16x8*)&Alds[buf][kc0    ][srow][0] = va[0];
        *(u16x8*)&Alds[buf][kc0 + 1][srow][0] = va[1];
        *(u16x8*)&Blds[buf][kc0    ][srow][0] = vb[0];
        *(u16x8*)&Blds[buf][kc0 + 1][srow][0] = vb[1];
    };
    f32x4 acc[4][4];
#pragma unroll
    for (int i = 0; i < 4; ++i)
#pragma unroll
        for (int j = 0; j < 4; ++j) acc[i][j] = (f32x4){0.f, 0.f, 0.f, 0.f};
    {
        f32x4 a[4], b[4];
        stage_load(0, a, b);
        stage_write(0, a, b, coef(0));
    }
    __syncthreads();
    const int NT = KDIM / 32;
    int cur = 0;
    for (int t = 0; t < NT; ++t) {
        f32x4 a[4], b[4];
        if (t + 1 < NT) stage_load(t + 1, a, b);
        s16x8 af[4], bf_[4];
#pragma unroll
        for (int i = 0; i < 4; ++i) {
            af[i]  = *(const s16x8*)&Alds[cur][kcl][arow0 + i * 16][0];
            bf_[i] = *(const s16x8*)&Blds[cur][kcl][brow0 + i * 16][0];
        }
#pragma unroll
        for (int i = 0; i < 4; ++i)
#pragma unroll
            for (int j = 0; j < 4; ++j)
                acc[i][j] = __builtin_amdgcn_mfma_f32_16x16x32_bf16(
                    af[i], bf_[j], acc[i][j], 0, 0, 0);
        if (t + 1 < NT) stage_write(cur ^ 1, a, b, coef(t + 1));
        __syncthreads();
        cur ^= 1;
    }
    const int gm0 = m_tile * 128 + (wv >> 1) * 64 + kcl * 4;
    const int gn0 = n_tile * 128 + (wv & 1) * 64 + frow;
#pragma unroll
    for (int j = 0; j < 4; ++j) {
        const int n = gn0 + j * 16;
        const float bc = bias[n] * row_bias_coef(n, w);
#pragma unroll
        for (int i = 0; i < 4; ++i) {
            float* yp = Y + (size_t)(gm0 + i * 16) * NDIM + n;
            yp[0 * NDIM] = acc[i][j][0] + bc;
            yp[1 * NDIM] = acc[i][j][1] + bc;
            yp[2 * NDIM] = acc[i][j][2] + bc;
            yp[3 * NDIM] = acc[i][j][3] + bc;
        }
    }
}

extern "C" void kernel_launch(void* const* d_in, const int* in_sizes, int n_in,
                              void* d_out, int out_size, void* d_ws, size_t ws_size,
                              hipStream_t stream) {
    const float* X    = (const float*)d_in[0];
    const float* wts  = (const float*)d_in[1];
    const float* W    = (const float*)d_in[2];
    const float* bias = (const float*)d_in[3];
    float* Y = (float*)d_out;

    const int M = in_sizes[0] / KDIM;            // 32768

    const size_t xb_elems = (size_t)M * KDIM;
    const size_t wb_elems = (size_t)NDIM * KDIM;
    const size_t ws_needed = (xb_elems + wb_elems) * sizeof(unsigned short);

    if (ws_size >= ws_needed && (M % 256) == 0) {
        unsigned short* XB = (unsigned short*)d_ws;
        unsigned short* WB = XB + xb_elems;
        prep_x<<<4096, 256, 0, stream>>>(X, XB, (int)(xb_elems / 8));
        prep_w<<<(NDIM * (KDIM / 8)) / 256, 256, 0, stream>>>(W, wts, WB);
        const int grid = (M / 256) * (NDIM / 256);   // 2048
        mlv2_gemm_v8<<<grid, 256, 0, stream>>>(XB, WB, wts, bias, Y);
    } else {
        const int grid = (M / 128) * (NDIM / 128);
        mlv2_gemm_v1<<<grid, 256, 0, stream>>>(X, wts, W, bias, Y);
    }
}

// Round 9
// 377.619 us; speedup vs baseline: 1.6884x; 1.6884x over previous
//
#include <hip/hip_runtime.h>

#define KDIM 1024
#define NDIM 4096

typedef __attribute__((ext_vector_type(4))) float f32x4;
typedef __attribute__((ext_vector_type(8))) short s16x8;
typedef __attribute__((ext_vector_type(8))) unsigned short u16x8;

__device__ __forceinline__ unsigned short f2bf(float f) {
    union { float f; unsigned u; } v; v.f = f;
    unsigned r = v.u + 0x7FFFu + ((v.u >> 16) & 1u);
    return (unsigned short)(r >> 16);
}

#define GLDS(gsrc, ldst)                                                        \
    __builtin_amdgcn_global_load_lds(                                           \
        (const __attribute__((address_space(1))) unsigned int*)(gsrc),          \
        (__attribute__((address_space(3))) unsigned int*)(ldst), 16, 0, 0)

#define SBAR() __builtin_amdgcn_s_barrier()
#define VMW(n) asm volatile("s_waitcnt vmcnt(" #n ")" ::: "memory")
#define LGKM0() asm volatile("s_waitcnt lgkmcnt(0)" ::: "memory")

__device__ __forceinline__ void row_coeffs(int o, const float* w,
                                           float& rp0, float& rp1, float& rp2) {
    rp2 = (o < 2048 ? w[6] : 0.f) + (o < 3072 ? w[7] : 0.f) + w[8];
    rp1 = rp2 + (o < 1536 ? w[3] : 0.f) + (o < 2304 ? w[4] : 0.f) + (o < 3072 ? w[5] : 0.f);
    rp0 = rp1 + (o < 1024 ? w[0] : 0.f) + (o < 1536 ? w[1] : 0.f) + (o < 2048 ? w[2] : 0.f);
}

__device__ __forceinline__ float row_bias_coef(int n, const float* w) {
    return (n < 1024 ? w[0] : 0.f) + (n < 1536 ? w[1] : 0.f)
         + (n < 2048 ? w[2] : 0.f) + (n < 1536 ? w[3] : 0.f)
         + (n < 2304 ? w[4] : 0.f) + (n < 3072 ? w[5] : 0.f)
         + (n < 2048 ? w[6] : 0.f) + (n < 3072 ? w[7] : 0.f) + w[8];
}

// ---------------- pre-pass: X f32 -> bf16 PANELS ----------------
// Panel p = m_tile*32 + kt: 16KB contiguous, chunk c (16B) = row*4 + kc_phys,
// kc_phys = kc_logical ^ ((row>>1)&3)  (LDS bank swizzle baked into layout).
// Writes: perfectly coalesced (out addr = g*16B). Reads: 4 consecutive threads
// cover one 128B line of a row (permuted within the line).
__global__ __launch_bounds__(256) void prep_x_p(const float* __restrict__ X,
                                                unsigned short* __restrict__ XB,
                                                int nchunks) {
    const int g = blockIdx.x * 256 + threadIdx.x;
    if (g >= nchunks) return;
    const int c   = g & 1023;          // chunk within panel
    const int p   = g >> 10;           // panel = m_tile*32 + kt
    const int kt  = p & 31;
    const int mt  = p >> 5;
    const int row = c >> 2;
    const int kcl = (c & 3) ^ ((row >> 1) & 3);
    const float* src = X + ((size_t)(mt * 256 + row) * KDIM + kt * 32 + kcl * 8);
    f32x4 a = *(const f32x4*)src, b = *(const f32x4*)(src + 4);
    u16x8 o;
    o[0] = f2bf(a[0]); o[1] = f2bf(a[1]); o[2] = f2bf(a[2]); o[3] = f2bf(a[3]);
    o[4] = f2bf(b[0]); o[5] = f2bf(b[1]); o[6] = f2bf(b[2]); o[7] = f2bf(b[3]);
    *(u16x8*)(XB + (size_t)g * 8) = o;
}

// ---------------- pre-pass: W_mix panels (same layout, coeff applied) ----------------
__global__ __launch_bounds__(256) void prep_w_p(const float* __restrict__ W,
                                                const float* __restrict__ wts,
                                                unsigned short* __restrict__ WB,
                                                int nchunks) {
    const int g = blockIdx.x * 256 + threadIdx.x;
    if (g >= nchunks) return;
    const int c   = g & 1023;
    const int p   = g >> 10;           // panel = n_tile*32 + kt
    const int kt  = p & 31;
    const int nt  = p >> 5;
    const int row = c >> 2;
    const int kcl = (c & 3) ^ ((row >> 1) & 3);
    float w[9];
#pragma unroll
    for (int k = 0; k < 9; ++k) w[k] = wts[k];
    float rp0, rp1, rp2;
    row_coeffs(nt * 256 + row, w, rp0, rp1, rp2);
    const int i0 = kt * 32 + kcl * 8;               // col-region constant per chunk
    const float cf = i0 < 512 ? rp0 : (i0 < 768 ? rp1 : rp2);
    const float* src = W + ((size_t)(nt * 256 + row) * KDIM + i0);
    f32x4 a = *(const f32x4*)src, b = *(const f32x4*)(src + 4);
    u16x8 o;
    o[0] = f2bf(a[0] * cf); o[1] = f2bf(a[1] * cf); o[2] = f2bf(a[2] * cf); o[3] = f2bf(a[3] * cf);
    o[4] = f2bf(b[0] * cf); o[5] = f2bf(b[1] * cf); o[6] = f2bf(b[2] * cf); o[7] = f2bf(b[3] * cf);
    *(u16x8*)(WB + (size_t)g * 8) = o;
}

// ---------------- main GEMM v9: v7 schedule + contiguous panel staging ----------------
// v7 (349us, MfmaUtil 35%) was staging-rate-bound: GLDS sources were strided
// row-gathers (16-64 cache lines per instruction). v9 sources are pre-tiled
// 16KB panels: lane l reads chunk base+l -> contiguous 1KB per GLDS, 100% line
// use (m97's pattern, ~52 B/cyc/CU). Schedule/geometry identical to v7:
// 256x256, 8 waves (2Mx4N), ring-4 LDS 128KiB, 1 barrier + VMW(8) per K-tile.
__global__ __launch_bounds__(512, 2) void mlv2_gemm_v9(
    const unsigned short* __restrict__ XB,   // panels [m_tile*32+kt][1024 chunks]
    const unsigned short* __restrict__ WB,   // panels [n_tile*32+kt][1024 chunks]
    const float* __restrict__ wts,
    const float* __restrict__ bias,
    float* __restrict__ Y)
{
    __shared__ unsigned short LDS[4 * 16384];   // 128 KiB: 4 bufs x (A 16KB + B 16KB)

    const int tid = (int)threadIdx.x;
    const int l   = tid & 63;
    const int w   = tid >> 6;      // wave 0..7
    const int wm  = w >> 2;        // 0..1
    const int wn  = w & 3;         // 0..3

    const int bid = (int)blockIdx.x;
    const int xcd = bid & 7;
    const int i   = bid >> 3;                // 0..255
    const int n_tile = xcd * 2 + (i & 1);    // XCD pinned to 2 n-tiles
    const int m_tile = i >> 1;               // pair shares m_tile
    const int m0 = m_tile * 256;
    const int n0 = n_tile * 256;

    // ---- frag-read offsets (ushort units); swizzle is a lane constant:
    // chunk(row,kc) = row*4 + (kc ^ ((row>>1)&3)), kc = l>>4, row%16 = rl
    const int rl = l & 15;
    const unsigned swz = (unsigned)((l >> 4) ^ ((rl >> 1) & 3));
    unsigned offA[8], offB[4];
#pragma unroll
    for (int m = 0; m < 8; ++m)
        offA[m] = ((unsigned)(wm * 128 + m * 16 + rl) * 4u + swz) * 8u;
#pragma unroll
    for (int n = 0; n < 4; ++n)
        offB[n] = 8192u + ((unsigned)(wn * 64 + n * 16 + rl) * 4u + swz) * 8u;

    // ---- staging: wave w stages panel chunks [w*128, w*128+128) of A and B.
    // Per-lane source chunk = base + l -> contiguous 1KB per GLDS. Linear dest.
    const unsigned cA0 = (unsigned)(w * 128 + l) * 8u;   // ushort offset in panel
    const unsigned cA1 = cA0 + 512u;                     // +64 chunks
    const unsigned dA0 = (unsigned)(w * 1024);           // LDS ushort offsets
    const unsigned dA1 = dA0 + 512u;
    const unsigned dB0 = 8192u + dA0;
    const unsigned dB1 = 8192u + dA1;

    auto stage = [&](int buf, int kt) {
        const unsigned short* pa = XB + ((size_t)(m_tile * 32 + kt) << 13);
        const unsigned short* pb = WB + ((size_t)(n_tile * 32 + kt) << 13);
        const unsigned ob = (unsigned)buf * 16384u;
        GLDS(pa + cA0, &LDS[ob + dA0]);
        GLDS(pa + cA1, &LDS[ob + dA1]);
        GLDS(pb + cA0, &LDS[ob + dB0]);
        GLDS(pb + cA1, &LDS[ob + dB1]);
    };

    f32x4 acc[8][4];
#pragma unroll
    for (int m = 0; m < 8; ++m)
#pragma unroll
        for (int n = 0; n < 4; ++n) acc[m][n] = (f32x4){0.f, 0.f, 0.f, 0.f};

    auto compute = [&](int buf) {
        const unsigned short* base = &LDS[(unsigned)buf * 16384u];
        s16x8 af[8], bfr[4];
#pragma unroll
        for (int n = 0; n < 4; ++n) bfr[n] = *(const s16x8*)(base + offB[n]);
#pragma unroll
        for (int m = 0; m < 8; ++m) af[m] = *(const s16x8*)(base + offA[m]);
        __builtin_amdgcn_s_setprio(1);
#pragma unroll
        for (int m = 0; m < 8; ++m)
#pragma unroll
            for (int n = 0; n < 4; ++n)
                acc[m][n] = __builtin_amdgcn_mfma_f32_16x16x32_bf16(
                    af[m], bfr[n], acc[m][n], 0, 0, 0);
        __builtin_amdgcn_s_setprio(0);
    };

    // prologue: stage kt 0,1,2 (12 loads); wait kt0 (8 stay in flight)
    stage(0, 0); stage(1, 1); stage(2, 2);
    VMW(8);
    SBAR();

    // steady: iter kt reads buf[kt&3]; stages kt+3 into buf[(kt+3)&3] (reads of
    // that buf retired at iter kt-1 via LGKM0). VMW(8): kt+1 guaranteed landed.
    for (int kt = 0; kt < 29; ++kt) {
        stage((kt + 3) & 3, kt + 3);
        compute(kt & 3);
        VMW(8); LGKM0(); SBAR();
    }
    compute(29 & 3);
    VMW(4); LGKM0(); SBAR();
    compute(30 & 3);
    VMW(0); LGKM0(); SBAR();
    compute(31 & 3);

    // ---- epilogue: + bias[n] * rowcoef(n)
    float w9[9];
#pragma unroll
    for (int k = 0; k < 9; ++k) w9[k] = wts[k];
    const int gmb = m0 + wm * 128 + (l >> 4) * 4;
    const int gnb = n0 + wn * 64 + rl;
#pragma unroll
    for (int n = 0; n < 4; ++n) {
        const int gn = gnb + n * 16;
        const float bc = bias[gn] * row_bias_coef(gn, w9);
#pragma unroll
        for (int m = 0; m < 8; ++m) {
            float* yp = Y + (size_t)(gmb + m * 16) * NDIM + gn;
            yp[0 * NDIM] = acc[m][n][0] + bc;
            yp[1 * NDIM] = acc[m][n][1] + bc;
            yp[2 * NDIM] = acc[m][n][2] + bc;
            yp[3 * NDIM] = acc[m][n][3] + bc;
        }
    }
}

// ---------------- fallback (round-1 fused kernel, validated) ----------------
__global__ __launch_bounds__(256, 2) void mlv2_gemm_v1(
    const float* __restrict__ X, const float* __restrict__ wts,
    const float* __restrict__ W, const float* __restrict__ bias,
    float* __restrict__ Y)
{
    __shared__ unsigned short Alds[2][4][128][8];
    __shared__ unsigned short Blds[2][4][128][8];
    const int tid = (int)threadIdx.x;
    const int bid = (int)blockIdx.x;
    const int wg  = (bid & 7) * 1024 + (bid >> 3);
    const int n_tile = wg & 31;
    const int m_tile = wg >> 5;
    float w[9];
#pragma unroll
    for (int k = 0; k < 9; ++k) w[k] = wts[k];
    const int srow = tid >> 1;
    const int scol = (tid & 1) << 4;
    const int kc0  = (tid & 1) << 1;
    const float* xp = X + (size_t)(m_tile * 128 + srow) * KDIM + scol;
    const float* wp = W + (size_t)(n_tile * 128 + srow) * KDIM + scol;
    const int orow = n_tile * 128 + srow;
    float rp0, rp1, rp2;
    row_coeffs(orow, w, rp0, rp1, rp2);
    const int lane = tid & 63, wv = tid >> 6;
    const int frow = lane & 15, kcl = lane >> 4;
    const int arow0 = (wv >> 1) * 64 + frow;
    const int brow0 = (wv & 1) * 64 + frow;
    auto coef = [&](int t) -> float { return t < 16 ? rp0 : (t < 24 ? rp1 : rp2); };
    auto stage_load = [&](int t, f32x4 a[4], f32x4 b[4]) {
        const f32x4* xq = (const f32x4*)(xp + t * 32);
        const f32x4* wq = (const f32x4*)(wp + t * 32);
#pragma unroll
        for (int j = 0; j < 4; ++j) { a[j] = xq[j]; b[j] = wq[j]; }
    };
    auto stage_write = [&](int buf, const f32x4 a[4], const f32x4 b[4], float cf) {
        u16x8 va[2], vb[2];
#pragma unroll
        for (int j = 0; j < 4; ++j)
#pragma unroll
            for (int e = 0; e < 4; ++e) {
                const int idx = j * 4 + e;
                va[idx >> 3][idx & 7] = f2bf(a[j][e]);
                vb[idx >> 3][idx & 7] = f2bf(b[j][e] * cf);
            }
        *(u16x8*)&Alds[buf][kc0    ][srow][0] = va[0];
        *(u16x8*)&Alds[buf][kc0 + 1][srow][0] = va[1];
        *(u16x8*)&Blds[buf][kc0    ][srow][0] = vb[0];
        *(u16x8*)&Blds[buf][kc0 + 1][srow][0] = vb[1];
    };
    f32x4 acc[4][4];
#pragma unroll
    for (int i = 0; i < 4; ++i)
#pragma unroll
        for (int j = 0; j < 4; ++j) acc[i][j] = (f32x4){0.f, 0.f, 0.f, 0.f};
    {
        f32x4 a[4], b[4];
        stage_load(0, a, b);
        stage_write(0, a, b, coef(0));
    }
    __syncthreads();
    const int NT = KDIM / 32;
    int cur = 0;
    for (int t = 0; t < NT; ++t) {
        f32x4 a[4], b[4];
        if (t + 1 < NT) stage_load(t + 1, a, b);
        s16x8 af[4], bf_[4];
#pragma unroll
        for (int i = 0; i < 4; ++i) {
            af[i]  = *(const s16x8*)&Alds[cur][kcl][arow0 + i * 16][0];
            bf_[i] = *(const s16x8*)&Blds[cur][kcl][brow0 + i * 16][0];
        }
#pragma unroll
        for (int i = 0; i < 4; ++i)
#pragma unroll
            for (int j = 0; j < 4; ++j)
                acc[i][j] = __builtin_amdgcn_mfma_f32_16x16x32_bf16(
                    af[i], bf_[j], acc[i][j], 0, 0, 0);
        if (t + 1 < NT) stage_write(cur ^ 1, a, b, coef(t + 1));
        __syncthreads();
        cur ^= 1;
    }
    const int gm0 = m_tile * 128 + (wv >> 1) * 64 + kcl * 4;
    const int gn0 = n_tile * 128 + (wv & 1) * 64 + frow;
#pragma unroll
    for (int j = 0; j < 4; ++j) {
        const int n = gn0 + j * 16;
        const float bc = bias[n] * row_bias_coef(n, w);
#pragma unroll
        for (int i = 0; i < 4; ++i) {
            float* yp = Y + (size_t)(gm0 + i * 16) * NDIM + n;
            yp[0 * NDIM] = acc[i][j][0] + bc;
            yp[1 * NDIM] = acc[i][j][1] + bc;
            yp[2 * NDIM] = acc[i][j][2] + bc;
            yp[3 * NDIM] = acc[i][j][3] + bc;
        }
    }
}

extern "C" void kernel_launch(void* const* d_in, const int* in_sizes, int n_in,
                              void* d_out, int out_size, void* d_ws, size_t ws_size,
                              hipStream_t stream) {
    const float* X    = (const float*)d_in[0];
    const float* wts  = (const float*)d_in[1];
    const float* W    = (const float*)d_in[2];
    const float* bias = (const float*)d_in[3];
    float* Y = (float*)d_out;

    const int M = in_sizes[0] / KDIM;            // 32768

    const size_t xb_elems = (size_t)M * KDIM;
    const size_t wb_elems = (size_t)NDIM * KDIM;
    const size_t ws_needed = (xb_elems + wb_elems) * sizeof(unsigned short);

    if (ws_size >= ws_needed && (M % 256) == 0) {
        unsigned short* XB = (unsigned short*)d_ws;
        unsigned short* WB = XB + xb_elems;
        const int xchunks = (int)(xb_elems / 8);     // 4,194,304
        const int wchunks = (int)(wb_elems / 8);     //   524,288
        prep_x_p<<<(xchunks + 255) / 256, 256, 0, stream>>>(X, XB, xchunks);
        prep_w_p<<<(wchunks + 255) / 256, 256, 0, stream>>>(W, wts, WB, wchunks);
        const int grid = (M / 256) * (NDIM / 256);   // 2048
        mlv2_gemm_v9<<<grid, 512, 0, stream>>>(XB, WB, wts, bias, Y);
    } else {
        const int grid = (M / 128) * (NDIM / 128);
        mlv2_gemm_v1<<<grid, 256, 0, stream>>>(X, wts, W, bias, Y);
    }
}

// Round 10
// 369.149 us; speedup vs baseline: 1.7272x; 1.0229x over previous
//
#include <hip/hip_runtime.h>

#define KDIM 1024
#define NDIM 4096

typedef __attribute__((ext_vector_type(4))) float f32x4;
typedef __attribute__((ext_vector_type(8))) short s16x8;
typedef __attribute__((ext_vector_type(8))) unsigned short u16x8;

__device__ __forceinline__ unsigned short f2bf(float f) {
    union { float f; unsigned u; } v; v.f = f;
    unsigned r = v.u + 0x7FFFu + ((v.u >> 16) & 1u);
    return (unsigned short)(r >> 16);
}

#define GLDS(gsrc, ldst)                                                        \
    __builtin_amdgcn_global_load_lds(                                           \
        (const __attribute__((address_space(1))) unsigned int*)(gsrc),          \
        (__attribute__((address_space(3))) unsigned int*)(ldst), 16, 0, 0)

#define SBAR() __builtin_amdgcn_s_barrier()
#define VMW(n) asm volatile("s_waitcnt vmcnt(" #n ")" ::: "memory")
#define LGKM0() asm volatile("s_waitcnt lgkmcnt(0)" ::: "memory")

__device__ __forceinline__ void row_coeffs(int o, const float* w,
                                           float& rp0, float& rp1, float& rp2) {
    rp2 = (o < 2048 ? w[6] : 0.f) + (o < 3072 ? w[7] : 0.f) + w[8];
    rp1 = rp2 + (o < 1536 ? w[3] : 0.f) + (o < 2304 ? w[4] : 0.f) + (o < 3072 ? w[5] : 0.f);
    rp0 = rp1 + (o < 1024 ? w[0] : 0.f) + (o < 1536 ? w[1] : 0.f) + (o < 2048 ? w[2] : 0.f);
}

__device__ __forceinline__ float row_bias_coef(int n, const float* w) {
    return (n < 1024 ? w[0] : 0.f) + (n < 1536 ? w[1] : 0.f)
         + (n < 2048 ? w[2] : 0.f) + (n < 1536 ? w[3] : 0.f)
         + (n < 2304 ? w[4] : 0.f) + (n < 3072 ? w[5] : 0.f)
         + (n < 2048 ? w[6] : 0.f) + (n < 3072 ? w[7] : 0.f) + w[8];
}

// ---------------- pre-pass: X -> bf16 panels of 128 rows x 32 k (8 KB) ----------------
// Panel p = m_tile*32 + kt (m_tile in [0,256)); chunk c in [0,512):
// row = c>>2, kc_phys = (c&3) ^ ((row>>1)&3)  (LDS bank swizzle baked in).
__global__ __launch_bounds__(256) void prep_x_p(const float* __restrict__ X,
                                                unsigned short* __restrict__ XB,
                                                int nchunks) {
    const int g = blockIdx.x * 256 + threadIdx.x;
    if (g >= nchunks) return;
    const int c   = g & 511;
    const int p   = g >> 9;            // m_tile*32 + kt
    const int kt  = p & 31;
    const int mt  = p >> 5;
    const int row = c >> 2;
    const int kcl = (c & 3) ^ ((row >> 1) & 3);
    const float* src = X + ((size_t)(mt * 128 + row) * KDIM + kt * 32 + kcl * 8);
    f32x4 a = *(const f32x4*)src, b = *(const f32x4*)(src + 4);
    u16x8 o;
    o[0] = f2bf(a[0]); o[1] = f2bf(a[1]); o[2] = f2bf(a[2]); o[3] = f2bf(a[3]);
    o[4] = f2bf(b[0]); o[5] = f2bf(b[1]); o[6] = f2bf(b[2]); o[7] = f2bf(b[3]);
    *(u16x8*)(XB + (size_t)g * 8) = o;
}

// ---------------- pre-pass: W_mix -> bf16 panels of 256 rows x 32 k (16 KB) ----------------
__global__ __launch_bounds__(256) void prep_w_p(const float* __restrict__ W,
                                                const float* __restrict__ wts,
                                                unsigned short* __restrict__ WB,
                                                int nchunks) {
    const int g = blockIdx.x * 256 + threadIdx.x;
    if (g >= nchunks) return;
    const int c   = g & 1023;
    const int p   = g >> 10;           // n_tile*32 + kt
    const int kt  = p & 31;
    const int nt  = p >> 5;
    const int row = c >> 2;
    const int kcl = (c & 3) ^ ((row >> 1) & 3);
    float w[9];
#pragma unroll
    for (int k = 0; k < 9; ++k) w[k] = wts[k];
    float rp0, rp1, rp2;
    row_coeffs(nt * 256 + row, w, rp0, rp1, rp2);
    const int i0 = kt * 32 + kcl * 8;
    const float cf = i0 < 512 ? rp0 : (i0 < 768 ? rp1 : rp2);
    const float* src = W + ((size_t)(nt * 256 + row) * KDIM + i0);
    f32x4 a = *(const f32x4*)src, b = *(const f32x4*)(src + 4);
    u16x8 o;
    o[0] = f2bf(a[0] * cf); o[1] = f2bf(a[1] * cf); o[2] = f2bf(a[2] * cf); o[3] = f2bf(a[3] * cf);
    o[4] = f2bf(b[0] * cf); o[5] = f2bf(b[1] * cf); o[6] = f2bf(b[2] * cf); o[7] = f2bf(b[3] * cf);
    *(u16x8*)(WB + (size_t)g * 8) = o;
}

// ---------------- main GEMM v10: 128x256 tile, 8 waves (64x64), 2 blocks/CU ----------------
// Cross-round measurement: GLDS return rate is ~1.3-1.7 B/cyc PER WAVE (v8:4w->5,
// v9:8w->10, v6:11w->18, m97:12w->21 B/cyc/CU). Fix: 16 waves/CU (2 blocks via
// launch_bounds(512,4) = 128 unified regs: acc 64 AGPR + ~55 VGPR) AND 25% less
// staging per FLOP (24 KB/K-tile at half a 256^2-tile's work). Ring-3 LDS 72KB
// (2 blocks = 144 <= 160), 3 GLDS/wave/K-tile, counted VMW(3), 1 barrier/K-tile.
// Single frag set: at 4 waves/SIMD, cross-wave overlap hides ds_read latency.
__global__ __launch_bounds__(512, 4) void mlv2_gemm_v10(
    const unsigned short* __restrict__ XB,   // panels [m_tile*32+kt][512 chunks]
    const unsigned short* __restrict__ WB,   // panels [n_tile*32+kt][1024 chunks]
    const float* __restrict__ wts,
    const float* __restrict__ bias,
    float* __restrict__ Y)
{
    __shared__ unsigned short LDS[3 * 12288];   // 72 KiB: 3 bufs x (A 8KB + B 16KB)

    const int tid = (int)threadIdx.x;
    const int l   = tid & 63;
    const int w   = tid >> 6;      // wave 0..7
    const int wm  = w >> 2;        // 0..1  (M half)
    const int wn  = w & 3;         // 0..3  (N quarter)

    const int bid = (int)blockIdx.x;
    const int xcd = bid & 7;
    const int i   = bid >> 3;                // 0..511
    const int n_tile = xcd * 2 + (i & 1);    // XCD pinned to 2 n-tiles (B L2-resident)
    const int m_tile = i >> 1;               // 0..255; pair shares m_tile
    const int m0 = m_tile * 128;
    const int n0 = n_tile * 256;

    // ---- frag-read offsets (ushort units); swizzle collapses to lane constant
    const int rl = l & 15;
    const unsigned swz = (unsigned)((l >> 4) ^ ((rl >> 1) & 3));
    unsigned offA[4], offB[4];
#pragma unroll
    for (int m = 0; m < 4; ++m)
        offA[m] = ((unsigned)(wm * 64 + m * 16 + rl) * 4u + swz) * 8u;
#pragma unroll
    for (int n = 0; n < 4; ++n)
        offB[n] = 4096u + ((unsigned)(wn * 64 + n * 16 + rl) * 4u + swz) * 8u;

    // ---- staging: 3 GLDS/wave: A chunks [w*64, +64); B chunks [w*128, +128)
    const unsigned cA  = (unsigned)(w * 64 + l) * 8u;     // ushort offset in A panel
    const unsigned cB0 = (unsigned)(w * 128 + l) * 8u;    // in B panel
    const unsigned cB1 = cB0 + 512u;
    const unsigned dA  = (unsigned)(w * 512);             // LDS ushort offsets in buf
    const unsigned dB0 = 4096u + (unsigned)(w * 1024);
    const unsigned dB1 = dB0 + 512u;

    auto stage = [&](unsigned ob, int kt) {
        const unsigned short* pa = XB + ((size_t)(m_tile * 32 + kt) << 12);  // 4096 ush/panel
        const unsigned short* pb = WB + ((size_t)(n_tile * 32 + kt) << 13);  // 8192 ush/panel
        GLDS(pa + cA,  &LDS[ob + dA]);
        GLDS(pb + cB0, &LDS[ob + dB0]);
        GLDS(pb + cB1, &LDS[ob + dB1]);
    };

    f32x4 acc[4][4];
#pragma unroll
    for (int m = 0; m < 4; ++m)
#pragma unroll
        for (int n = 0; n < 4; ++n) acc[m][n] = (f32x4){0.f, 0.f, 0.f, 0.f};

    auto compute = [&](unsigned ob) {
        const unsigned short* base = &LDS[ob];
        s16x8 a[4], b[4];
#pragma unroll
        for (int n = 0; n < 4; ++n) b[n] = *(const s16x8*)(base + offB[n]);
#pragma unroll
        for (int m = 0; m < 4; ++m) a[m] = *(const s16x8*)(base + offA[m]);
        __builtin_amdgcn_s_setprio(1);
#pragma unroll
        for (int m = 0; m < 4; ++m)
#pragma unroll
            for (int n = 0; n < 4; ++n)
                acc[m][n] = __builtin_amdgcn_mfma_f32_16x16x32_bf16(
                    a[m], b[n], acc[m][n], 0, 0, 0);
        __builtin_amdgcn_s_setprio(0);
    };

    // prologue: stage kt0, kt1 (6 loads); wait kt0 (kt1's 3 in flight)
    unsigned o0 = 0, o1 = 12288, o2 = 24576;
    stage(o0, 0); stage(o1, 1);
    VMW(3);
    SBAR();

    // steady: iter kt: stage(kt+2)->o2 | read+MFMA(o0=kt) | VMW(3) [kt+1 landed] | bar
    // Buf safety: o2 held kt-1's data, whose reads retired via LGKM0 before iter
    // kt-1's barrier; staged again only after that barrier.
    for (int kt = 0; kt < 30; ++kt) {
        stage(o2, kt + 2);
        compute(o0);
        VMW(3); LGKM0(); SBAR();
        const unsigned t_ = o0; o0 = o1; o1 = o2; o2 = t_;
    }
    // kt=30: drain kt31's loads
    compute(o0);
    VMW(0); LGKM0(); SBAR();
    // kt=31
    compute(o1);

    // ---- epilogue: + bias[n] * rowcoef(n)
    float w9[9];
#pragma unroll
    for (int k = 0; k < 9; ++k) w9[k] = wts[k];
    const int gmb = m0 + wm * 64 + (l >> 4) * 4;
    const int gnb = n0 + wn * 64 + rl;
#pragma unroll
    for (int n = 0; n < 4; ++n) {
        const int gn = gnb + n * 16;
        const float bc = bias[gn] * row_bias_coef(gn, w9);
#pragma unroll
        for (int m = 0; m < 4; ++m) {
            float* yp = Y + (size_t)(gmb + m * 16) * NDIM + gn;
            yp[0 * NDIM] = acc[m][n][0] + bc;
            yp[1 * NDIM] = acc[m][n][1] + bc;
            yp[2 * NDIM] = acc[m][n][2] + bc;
            yp[3 * NDIM] = acc[m][n][3] + bc;
        }
    }
}

// ---------------- fallback (round-1 fused kernel, validated) ----------------
__global__ __launch_bounds__(256, 2) void mlv2_gemm_v1(
    const float* __restrict__ X, const float* __restrict__ wts,
    const float* __restrict__ W, const float* __restrict__ bias,
    float* __restrict__ Y)
{
    __shared__ unsigned short Alds[2][4][128][8];
    __shared__ unsigned short Blds[2][4][128][8];
    const int tid = (int)threadIdx.x;
    const int bid = (int)blockIdx.x;
    const int wg  = (bid & 7) * 1024 + (bid >> 3);
    const int n_tile = wg & 31;
    const int m_tile = wg >> 5;
    float w[9];
#pragma unroll
    for (int k = 0; k < 9; ++k) w[k] = wts[k];
    const int srow = tid >> 1;
    const int scol = (tid & 1) << 4;
    const int kc0  = (tid & 1) << 1;
    const float* xp = X + (size_t)(m_tile * 128 + srow) * KDIM + scol;
    const float* wp = W + (size_t)(n_tile * 128 + srow) * KDIM + scol;
    const int orow = n_tile * 128 + srow;
    float rp0, rp1, rp2;
    row_coeffs(orow, w, rp0, rp1, rp2);
    const int lane = tid & 63, wv = tid >> 6;
    const int frow = lane & 15, kcl = lane >> 4;
    const int arow0 = (wv >> 1) * 64 + frow;
    const int brow0 = (wv & 1) * 64 + frow;
    auto coef = [&](int t) -> float { return t < 16 ? rp0 : (t < 24 ? rp1 : rp2); };
    auto stage_load = [&](int t, f32x4 a[4], f32x4 b[4]) {
        const f32x4* xq = (const f32x4*)(xp + t * 32);
        const f32x4* wq = (const f32x4*)(wp + t * 32);
#pragma unroll
        for (int j = 0; j < 4; ++j) { a[j] = xq[j]; b[j] = wq[j]; }
    };
    auto stage_write = [&](int buf, const f32x4 a[4], const f32x4 b[4], float cf) {
        u16x8 va[2], vb[2];
#pragma unroll
        for (int j = 0; j < 4; ++j)
#pragma unroll
            for (int e = 0; e < 4; ++e) {
                const int idx = j * 4 + e;
                va[idx >> 3][idx & 7] = f2bf(a[j][e]);
                vb[idx >> 3][idx & 7] = f2bf(b[j][e] * cf);
            }
        *(u16x8*)&Alds[buf][kc0    ][srow][0] = va[0];
        *(u16x8*)&Alds[buf][kc0 + 1][srow][0] = va[1];
        *(u16x8*)&Blds[buf][kc0    ][srow][0] = vb[0];
        *(u16x8*)&Blds[buf][kc0 + 1][srow][0] = vb[1];
    };
    f32x4 acc[4][4];
#pragma unroll
    for (int i = 0; i < 4; ++i)
#pragma unroll
        for (int j = 0; j < 4; ++j) acc[i][j] = (f32x4){0.f, 0.f, 0.f, 0.f};
    {
        f32x4 a[4], b[4];
        stage_load(0, a, b);
        stage_write(0, a, b, coef(0));
    }
    __syncthreads();
    const int NT = KDIM / 32;
    int cur = 0;
    for (int t = 0; t < NT; ++t) {
        f32x4 a[4], b[4];
        if (t + 1 < NT) stage_load(t + 1, a, b);
        s16x8 af[4], bf_[4];
#pragma unroll
        for (int i = 0; i < 4; ++i) {
            af[i]  = *(const s16x8*)&Alds[cur][kcl][arow0 + i * 16][0];
            bf_[i] = *(const s16x8*)&Blds[cur][kcl][brow0 + i * 16][0];
        }
#pragma unroll
        for (int i = 0; i < 4; ++i)
#pragma unroll
            for (int j = 0; j < 4; ++j)
                acc[i][j] = __builtin_amdgcn_mfma_f32_16x16x32_bf16(
                    af[i], bf_[j], acc[i][j], 0, 0, 0);
        if (t + 1 < NT) stage_write(cur ^ 1, a, b, coef(t + 1));
        __syncthreads();
        cur ^= 1;
    }
    const int gm0 = m_tile * 128 + (wv >> 1) * 64 + kcl * 4;
    const int gn0 = n_tile * 128 + (wv & 1) * 64 + frow;
#pragma unroll
    for (int j = 0; j < 4; ++j) {
        const int n = gn0 + j * 16;
        const float bc = bias[n] * row_bias_coef(n, w);
#pragma unroll
        for (int i = 0; i < 4; ++i) {
            float* yp = Y + (size_t)(gm0 + i * 16) * NDIM + n;
            yp[0 * NDIM] = acc[i][j][0] + bc;
            yp[1 * NDIM] = acc[i][j][1] + bc;
            yp[2 * NDIM] = acc[i][j][2] + bc;
            yp[3 * NDIM] = acc[i][j][3] + bc;
        }
    }
}

extern "C" void kernel_launch(void* const* d_in, const int* in_sizes, int n_in,
                              void* d_out, int out_size, void* d_ws, size_t ws_size,
                              hipStream_t stream) {
    const float* X    = (const float*)d_in[0];
    const float* wts  = (const float*)d_in[1];
    const float* W    = (const float*)d_in[2];
    const float* bias = (const float*)d_in[3];
    float* Y = (float*)d_out;

    const int M = in_sizes[0] / KDIM;            // 32768

    const size_t xb_elems = (size_t)M * KDIM;
    const size_t wb_elems = (size_t)NDIM * KDIM;
    const size_t ws_needed = (xb_elems + wb_elems) * sizeof(unsigned short);

    if (ws_size >= ws_needed && (M % 128) == 0) {
        unsigned short* XB = (unsigned short*)d_ws;
        unsigned short* WB = XB + xb_elems;
        const int xchunks = (int)(xb_elems / 8);     // 4,194,304
        const int wchunks = (int)(wb_elems / 8);     //   524,288
        prep_x_p<<<(xchunks + 255) / 256, 256, 0, stream>>>(X, XB, xchunks);
        prep_w_p<<<(wchunks + 255) / 256, 256, 0, stream>>>(W, wts, WB, wchunks);
        const int grid = (M / 128) * (NDIM / 256);   // 4096
        mlv2_gemm_v10<<<grid, 512, 0, stream>>>(XB, WB, wts, bias, Y);
    } else {
        const int grid = (M / 128) * (NDIM / 128);
        mlv2_gemm_v1<<<grid, 256, 0, stream>>>(X, wts, W, bias, Y);
    }
}